// Round 5
// baseline (435.582 us; speedup 1.0000x reference)
//
#include <hip/hip_runtime.h>
#include <hip/hip_bf16.h>
#include <stdint.h>

typedef unsigned short u16;
typedef __attribute__((__vector_size__(16))) short s16x8;
typedef __attribute__((__vector_size__(16))) float f32x4;

#define N_ 16384
#define C_ 256

__device__ __forceinline__ u16 f2bf(float f) {
    union { uint32_t i; float f; } v; v.f = f;
    uint32_t u = v.i;
    return (u16)((u + 0x7FFFu + ((u >> 16) & 1u)) >> 16);
}

// async global->LDS, 16 B per lane. LDS dest = wave-uniform base + lane*16.
__device__ __forceinline__ void gl_lds16(const u16* g, u16* l) {
    __builtin_amdgcn_global_load_lds((__attribute__((address_space(1))) void*)g,
                                     (__attribute__((address_space(3))) void*)l,
                                     16, 0, 0);
}

__global__ __launch_bounds__(256) void zero_kernel(float* __restrict__ p, int n) {
    int i = blockIdx.x * 256 + threadIdx.x;
    if (i < n) p[i] = 0.f;
}

// ---------------------------------------------------------------------------
// K0: x fp32 [B][C][N] -> xT bf16 [B][N][C]
// ---------------------------------------------------------------------------
__global__ __launch_bounds__(256) void transpose_kernel(const float* __restrict__ x,
                                                        u16* __restrict__ xT) {
    __shared__ float T[64][65];
    int tid = threadIdx.x;
    int n0 = blockIdx.x * 64, c0 = blockIdx.y * 64, b = blockIdx.z;
    const float* xp = x + (size_t)b * C_ * N_;
    for (int it = 0; it < 16; it++) {
        int idx = it * 256 + tid;
        int c = idx >> 6, n = idx & 63;
        T[c][n] = xp[(size_t)(c0 + c) * N_ + n0 + n];
    }
    __syncthreads();
    u16* op = xT + (size_t)b * N_ * C_;
    for (int it = 0; it < 8; it++) {
        int idx = it * 256 + tid;
        int n = idx >> 5, c2 = (idx & 31) * 2;
        uint32_t lo = f2bf(T[c2][n]);
        uint32_t hi = f2bf(T[c2 + 1][n]);
        *(uint32_t*)&op[(size_t)(n0 + n) * C_ + c0 + c2] = lo | (hi << 16);
    }
}

// ---------------------------------------------------------------------------
// Kw: wq/wk/wv fp32 -> wb bf16 [3][512][256]
// ---------------------------------------------------------------------------
__global__ __launch_bounds__(256) void cvtw_kernel(const float* __restrict__ wq,
                                                   const float* __restrict__ wk,
                                                   const float* __restrict__ wv,
                                                   u16* __restrict__ wb) {
    int m = blockIdx.y;
    const float* s = m == 0 ? wq : (m == 1 ? wk : wv);
    int i = blockIdx.x * 256 + threadIdx.x;
    wb[(size_t)m * 131072 + i] = f2bf(s[i]);
}

// ---------------------------------------------------------------------------
// K1: fused k,v projection + LN + exp(k) + rowsum + ctx partial GEMM.
// Block = (n-tile 128, head-pair, batch). grid (128, 4, 4), 256 thr.
// LDS 64 KB: [WS 16K | XS 16K | VT 32K]; ET (32K) overlays WS+XS after k-proj.
// ctx[b,h,kd,vd] += sum_n eK[kd,n] V[vd,n] via fp32 global atomics.
// ---------------------------------------------------------------------------
__global__ __launch_bounds__(256) void kv_ctx_kernel(
    const u16* __restrict__ xT, const u16* __restrict__ wb,
    const float* __restrict__ bk, const float* __restrict__ bv,
    const float* __restrict__ gk, const float* __restrict__ bek,
    const float* __restrict__ gv, const float* __restrict__ bev,
    float* __restrict__ ctx_acc, float* __restrict__ rs)
{
    __shared__ u16 LDSU[32768];          // 64 KB
    u16* WS = LDSU;                      // [128][64] staging (proj)
    u16* XS = LDSU + 8192;               // [128][64] staging (proj)
    u16* VT = LDSU + 16384;              // [128][128] V tile (swizzled)
    u16* ET = LDSU;                      // [128][128] eK tile (overlays WS+XS)

    int tid = threadIdx.x;
    int lane = tid & 63, wid = tid >> 6;
    int quad = lane >> 4, l15 = lane & 15;
    int wm = wid >> 1, wn = wid & 1;
    int bx = blockIdx.x, pair = blockIdx.y, b = blockIdx.z;
    int n0 = bx * 128;
    int head = pair * 2 + wm;

    const u16* xsrc = xT + ((size_t)b * N_ + n0) * 256;
    int srow = lane >> 3;
    int sc8  = ((lane & 7) ^ srow) * 8;

    for (int kind = 0; kind < 2; kind++) {   // 0 = v, 1 = k
        const u16* wsrc = wb + (size_t)(2 - kind) * 131072 + (size_t)pair * 128 * 256;
        const float* bptr  = kind ? bk  : bv;
        const float* gptr  = kind ? gk  : gv;
        const float* beptr = kind ? bek : bev;

        f32x4 acc[4][4];
#pragma unroll
        for (int i = 0; i < 4; i++)
#pragma unroll
            for (int j = 0; j < 4; j++) acc[i][j] = (f32x4){0.f, 0.f, 0.f, 0.f};

        for (int kc = 0; kc < 4; kc++) {
            int koff = kc * 64 + sc8;
#pragma unroll
            for (int i = 0; i < 4; i++) {
                int rg = wid * 4 + i;
                gl_lds16(&wsrc[(size_t)(rg * 8 + srow) * 256 + koff], &WS[rg * 512]);
                gl_lds16(&xsrc[(size_t)(rg * 8 + srow) * 256 + koff], &XS[rg * 512]);
            }
            __syncthreads();
#pragma unroll
            for (int ks = 0; ks < 2; ks++) {
                int cc = ks * 4 + quad;
                s16x8 af[4], bf[4];
#pragma unroll
                for (int f = 0; f < 4; f++) {
                    int ar = wn * 64 + f * 16 + l15;   // A = x/n side
                    int br = wm * 64 + f * 16 + l15;   // B = weight side
                    af[f] = *(const s16x8*)&XS[ar * 64 + ((cc ^ (ar & 7)) * 8)];
                    bf[f] = *(const s16x8*)&WS[br * 64 + ((cc ^ (br & 7)) * 8)];
                }
#pragma unroll
                for (int i = 0; i < 4; i++)
#pragma unroll
                    for (int j = 0; j < 4; j++)
                        acc[i][j] = __builtin_amdgcn_mfma_f32_16x16x32_bf16(af[i], bf[j], acc[i][j], 0, 0, 0);
            }
            __syncthreads();
        }

        // epilogue: value(mf,nf,reg): n_loc = wn*64+mf*16+quad*4+reg,
        //           head-row rl = nf*16+l15
        float bB_[4], gB[4], eB[4];
#pragma unroll
        for (int nf = 0; nf < 4; nf++) {
            int rl = nf * 16 + l15;
            bB_[nf] = bptr[head * 64 + rl];
            gB[nf]  = gptr[rl];
            eB[nf]  = beptr[rl];
        }
#pragma unroll
        for (int mf = 0; mf < 4; mf++)
#pragma unroll
            for (int nf = 0; nf < 4; nf++)
#pragma unroll
                for (int r = 0; r < 4; r++) acc[mf][nf][r] += bB_[nf];
        float sa[4][4], sb[4][4];
#pragma unroll
        for (int mf = 0; mf < 4; mf++)
#pragma unroll
            for (int r = 0; r < 4; r++) {
                float s = 0.f, s2 = 0.f;
#pragma unroll
                for (int nf = 0; nf < 4; nf++) { float v = acc[mf][nf][r]; s += v; s2 += v * v; }
                sa[mf][r] = s; sb[mf][r] = s2;
            }
#pragma unroll
        for (int msk = 1; msk <= 8; msk <<= 1)
#pragma unroll
            for (int mf = 0; mf < 4; mf++)
#pragma unroll
                for (int r = 0; r < 4; r++) {
                    sa[mf][r] += __shfl_xor(sa[mf][r], msk);
                    sb[mf][r] += __shfl_xor(sb[mf][r], msk);
                }
#pragma unroll
        for (int mf = 0; mf < 4; mf++)
#pragma unroll
            for (int r = 0; r < 4; r++) {
                float mu = sa[mf][r] * (1.f / 64.f);
                float rstd = rsqrtf(sb[mf][r] * (1.f / 64.f) - mu * mu + 1e-5f);
#pragma unroll
                for (int nf = 0; nf < 4; nf++)
                    acc[mf][nf][r] = (acc[mf][nf][r] - mu) * rstd * gB[nf] + eB[nf];
            }
        if (kind == 1) {
#pragma unroll
            for (int mf = 0; mf < 4; mf++)
#pragma unroll
                for (int nf = 0; nf < 4; nf++)
#pragma unroll
                    for (int r = 0; r < 4; r++) acc[mf][nf][r] = __expf(acc[mf][nf][r]);
#pragma unroll
            for (int nf = 0; nf < 4; nf++) {
                float s = 0.f;
#pragma unroll
                for (int mf = 0; mf < 4; mf++)
#pragma unroll
                    for (int r = 0; r < 4; r++) s += acc[mf][nf][r];
                s += __shfl_xor(s, 16); s += __shfl_xor(s, 32);
                if (quad == 0)
                    atomicAdd(&rs[(size_t)b * 512 + head * 64 + nf * 16 + l15], s);
            }
        }
        // store tile to LDS (swizzled, same formula as R4 blocked tiles)
        u16* dst = kind ? ET : VT;   // ET overlays WS/XS: safe, kc loop ended with barrier
#pragma unroll
        for (int mf = 0; mf < 4; mf++)
#pragma unroll
            for (int nf = 0; nf < 4; nf++) {
                int rh = wm * 64 + nf * 16 + l15;          // tile row (proj row)
                int ln = wn * 64 + mf * 16 + quad * 4;     // tile col (n)
                int c  = ln >> 3;
                int off = rh * 128 + ((c ^ (rh & 15)) * 8) + (ln & 7);
                uint64_t w0 = (uint64_t)f2bf(acc[mf][nf][0]) | ((uint64_t)f2bf(acc[mf][nf][1]) << 16) |
                              ((uint64_t)f2bf(acc[mf][nf][2]) << 32) | ((uint64_t)f2bf(acc[mf][nf][3]) << 48);
                *(uint64_t*)&dst[off] = w0;
            }
    }
    __syncthreads();

    // ctx partial: wave = (head hh, K-half kh). acc 64x64 per head over K=64 n.
    int hh = wid >> 1, kh = wid & 1;
    f32x4 accc[4][4];
#pragma unroll
    for (int i = 0; i < 4; i++)
#pragma unroll
        for (int j = 0; j < 4; j++) accc[i][j] = (f32x4){0.f, 0.f, 0.f, 0.f};
#pragma unroll
    for (int ks = 0; ks < 2; ks++) {
        int cc = kh * 8 + ks * 4 + quad;
        s16x8 af[4], bf[4];
#pragma unroll
        for (int f = 0; f < 4; f++) {
            int off = (hh * 64 + f * 16 + l15) * 128 + ((cc ^ l15) * 8);
            af[f] = *(const s16x8*)&ET[off];
            bf[f] = *(const s16x8*)&VT[off];
        }
#pragma unroll
        for (int i = 0; i < 4; i++)
#pragma unroll
            for (int j = 0; j < 4; j++)
                accc[i][j] = __builtin_amdgcn_mfma_f32_16x16x32_bf16(af[i], bf[j], accc[i][j], 0, 0, 0);
    }
    size_t base = (size_t)(b * 8 + pair * 2 + hh) * 4096;
#pragma unroll
    for (int mf = 0; mf < 4; mf++)
#pragma unroll
        for (int nf = 0; nf < 4; nf++)
#pragma unroll
            for (int r = 0; r < 4; r++)
                atomicAdd(&ctx_acc[base + (size_t)(mf * 16 + quad * 4 + r) * 64 + nf * 16 + l15],
                          accc[mf][nf][r]);
}

// ---------------------------------------------------------------------------
// K3: Weff[b][c][h*64+kd] = sum_vd wo[c][h*64+vd] * (ctx/rs)
// ---------------------------------------------------------------------------
__global__ __launch_bounds__(256) void weff_kernel(
    const float* __restrict__ ctx_acc, const float* __restrict__ rs,
    const float* __restrict__ wo, u16* __restrict__ Weffb)
{
    __shared__ float CT[16][65];
    int tid = threadIdx.x;
    int h = blockIdx.x, b = blockIdx.y, kc = blockIdx.z;
    for (int i = tid; i < 1024; i += 256) {
        int kdl = i >> 6, vd = i & 63;
        int kd = kc * 16 + kdl;
        CT[kdl][vd] = ctx_acc[(((size_t)b * 8 + h) * 64 + kd) * 64 + vd] /
                      rs[(size_t)b * 512 + h * 64 + kd];
    }
    __syncthreads();
    int c = tid;
    float wrow[64];
    const float4* wp = (const float4*)(wo + (size_t)c * 512 + h * 64);
#pragma unroll
    for (int i = 0; i < 16; i++) { float4 t = wp[i]; wrow[i*4] = t.x; wrow[i*4+1] = t.y; wrow[i*4+2] = t.z; wrow[i*4+3] = t.w; }
    for (int kdl = 0; kdl < 16; kdl++) {
        float s = 0.f;
#pragma unroll
        for (int vd = 0; vd < 64; vd++) s += wrow[vd] * CT[kdl][vd];
        Weffb[((size_t)b * 256 + c) * 512 + h * 64 + kc * 16 + kdl] = f2bf(s);
    }
}

// ---------------------------------------------------------------------------
// K4: fused q projection + LN + softmax(dim) + out GEMM.
// Block = (n-tile 64, batch). grid (256, 4), 256 thr.
// Per pair (128 q-rows): proj -> softmax -> P to LDS -> out_acc += Weff @ P.
// Weff A-fragments load directly from global (L2-resident, 256 KB).
// ---------------------------------------------------------------------------
__global__ __launch_bounds__(256) void q_out_kernel(
    const u16* __restrict__ xT, const u16* __restrict__ wb,
    const float* __restrict__ bq, const float* __restrict__ gq, const float* __restrict__ beq,
    const u16* __restrict__ Weffb, const float* __restrict__ bo, float* __restrict__ out)
{
    __shared__ u16 WS[8192];   // W tile [128][64]
    __shared__ u16 XS[4096];   // x tile [64 n][64 k]
    __shared__ u16 PT[8192];   // P tile [64 n][128 r] swizzled
    int tid = threadIdx.x;
    int lane = tid & 63, wid = tid >> 6;
    int quad = lane >> 4, l15 = lane & 15;
    int wm = wid >> 1, wn = wid & 1;       // proj: wave = 64 r x 32 n
    int bx = blockIdx.x, b = blockIdx.y;
    int n0 = bx * 64;

    const u16* xsrc = xT + ((size_t)b * N_ + n0) * 256;
    int srow = lane >> 3;
    int sc8  = ((lane & 7) ^ srow) * 8;

    f32x4 acco[4][4];   // out acc: wave c-range wid*64, n 64
#pragma unroll
    for (int i = 0; i < 4; i++)
#pragma unroll
        for (int j = 0; j < 4; j++) acco[i][j] = (f32x4){0.f, 0.f, 0.f, 0.f};

    for (int pair = 0; pair < 4; pair++) {
        const u16* wsrc = wb + (size_t)pair * 128 * 256;   // q weights rows pair*128
        f32x4 acc[4][2];
#pragma unroll
        for (int i = 0; i < 4; i++)
#pragma unroll
            for (int j = 0; j < 2; j++) acc[i][j] = (f32x4){0.f, 0.f, 0.f, 0.f};

        for (int kc = 0; kc < 4; kc++) {
            int koff = kc * 64 + sc8;
#pragma unroll
            for (int i = 0; i < 4; i++) {
                int rg = wid * 4 + i;
                gl_lds16(&wsrc[(size_t)(rg * 8 + srow) * 256 + koff], &WS[rg * 512]);
            }
#pragma unroll
            for (int i = 0; i < 2; i++) {
                int rg = wid * 2 + i;
                gl_lds16(&xsrc[(size_t)(rg * 8 + srow) * 256 + koff], &XS[rg * 512]);
            }
            __syncthreads();
#pragma unroll
            for (int ks = 0; ks < 2; ks++) {
                int cc = ks * 4 + quad;
                s16x8 af[4], bf[2];
#pragma unroll
                for (int f = 0; f < 4; f++) {
                    int ar = wm * 64 + f * 16 + l15;   // A = weight side
                    af[f] = *(const s16x8*)&WS[ar * 64 + ((cc ^ (ar & 7)) * 8)];
                }
#pragma unroll
                for (int f = 0; f < 2; f++) {
                    int br = wn * 32 + f * 16 + l15;   // B = x/n side
                    bf[f] = *(const s16x8*)&XS[br * 64 + ((cc ^ (br & 7)) * 8)];
                }
#pragma unroll
                for (int i = 0; i < 4; i++)
#pragma unroll
                    for (int j = 0; j < 2; j++)
                        acc[i][j] = __builtin_amdgcn_mfma_f32_16x16x32_bf16(af[i], bf[j], acc[i][j], 0, 0, 0);
            }
            __syncthreads();
        }

        // epilogue: value(mf,nf,reg): row rl = mf*16+quad*4+reg (within head),
        //           col n = wn*32+nf*16+l15
#pragma unroll
        for (int mf = 0; mf < 4; mf++)
#pragma unroll
            for (int r = 0; r < 4; r++) {
                int rl = mf * 16 + quad * 4 + r;
                float bb = bq[pair * 128 + wm * 64 + rl];
#pragma unroll
                for (int nf = 0; nf < 2; nf++) acc[mf][nf][r] += bb;
            }
#pragma unroll
        for (int nf = 0; nf < 2; nf++) {
            float s = 0.f, s2 = 0.f;
#pragma unroll
            for (int mf = 0; mf < 4; mf++)
#pragma unroll
                for (int r = 0; r < 4; r++) { float v = acc[mf][nf][r]; s += v; s2 += v * v; }
            s  += __shfl_xor(s, 16);  s  += __shfl_xor(s, 32);
            s2 += __shfl_xor(s2, 16); s2 += __shfl_xor(s2, 32);
            float mu = s * (1.f / 64.f);
            float rstd = rsqrtf(s2 * (1.f / 64.f) - mu * mu + 1e-5f);
#pragma unroll
            for (int mf = 0; mf < 4; mf++)
#pragma unroll
                for (int r = 0; r < 4; r++) {
                    int rl = mf * 16 + quad * 4 + r;
                    acc[mf][nf][r] = (acc[mf][nf][r] - mu) * rstd * gq[rl] + beq[rl];
                }
        }
        const float s_q = 0.35355339059327373f;
#pragma unroll
        for (int nf = 0; nf < 2; nf++) {
            float m = -1e30f;
#pragma unroll
            for (int mf = 0; mf < 4; mf++)
#pragma unroll
                for (int r = 0; r < 4; r++) { acc[mf][nf][r] *= s_q; m = fmaxf(m, acc[mf][nf][r]); }
            m = fmaxf(m, __shfl_xor(m, 16)); m = fmaxf(m, __shfl_xor(m, 32));
            float d = 0.f;
#pragma unroll
            for (int mf = 0; mf < 4; mf++)
#pragma unroll
                for (int r = 0; r < 4; r++) { float e = __expf(acc[mf][nf][r] - m); acc[mf][nf][r] = e; d += e; }
            d += __shfl_xor(d, 16); d += __shfl_xor(d, 32);
            float inv = 1.f / d;
#pragma unroll
            for (int mf = 0; mf < 4; mf++)
#pragma unroll
                for (int r = 0; r < 4; r++) acc[mf][nf][r] *= inv;
        }
        // store P to PT: [n_loc 64][r_loc 128] swizzled
#pragma unroll
        for (int mf = 0; mf < 4; mf++)
#pragma unroll
            for (int nf = 0; nf < 2; nf++) {
                int nl = wn * 32 + nf * 16 + l15;
                int rl = wm * 64 + mf * 16 + quad * 4;
                int c  = rl >> 3;
                int off = nl * 128 + ((c ^ (nl & 15)) * 8) + (rl & 7);
                uint64_t w0 = (uint64_t)f2bf(acc[mf][nf][0]) | ((uint64_t)f2bf(acc[mf][nf][1]) << 16) |
                              ((uint64_t)f2bf(acc[mf][nf][2]) << 32) | ((uint64_t)f2bf(acc[mf][nf][3]) << 48);
                *(uint64_t*)&PT[off] = w0;
            }
        __syncthreads();

        // out partial: A = Weff[c][pair*128 + r] (global), B = PT
#pragma unroll
        for (int ks = 0; ks < 4; ks++) {
            int cc = ks * 4 + quad;
            s16x8 af[4], bf[4];
#pragma unroll
            for (int f = 0; f < 4; f++)
                af[f] = *(const s16x8*)&Weffb[((size_t)(b * 256 + wid * 64 + f * 16 + l15)) * 512 +
                                              pair * 128 + cc * 8];
#pragma unroll
            for (int f = 0; f < 4; f++)
                bf[f] = *(const s16x8*)&PT[(f * 16 + l15) * 128 + ((cc ^ l15) * 8)];
#pragma unroll
            for (int i = 0; i < 4; i++)
#pragma unroll
                for (int j = 0; j < 4; j++)
                    acco[i][j] = __builtin_amdgcn_mfma_f32_16x16x32_bf16(af[i], bf[j], acco[i][j], 0, 0, 0);
        }
        __syncthreads();   // PT/WS/XS reused next pair
    }

#pragma unroll
    for (int mf = 0; mf < 4; mf++)
#pragma unroll
        for (int r = 0; r < 4; r++) {
            int c = wid * 64 + mf * 16 + quad * 4 + r;
            float bb = bo[c];
#pragma unroll
            for (int nf = 0; nf < 4; nf++)
                out[((size_t)(b * 256 + c)) * N_ + n0 + nf * 16 + l15] = acco[mf][nf][r] + bb;
        }
}

extern "C" void kernel_launch(void* const* d_in, const int* in_sizes, int n_in,
                              void* d_out, int out_size, void* d_ws, size_t ws_size,
                              hipStream_t stream) {
    const float* x   = (const float*)d_in[0];
    const float* wq  = (const float*)d_in[1];
    const float* bq  = (const float*)d_in[2];
    const float* wk  = (const float*)d_in[3];
    const float* bk  = (const float*)d_in[4];
    const float* wv  = (const float*)d_in[5];
    const float* bv  = (const float*)d_in[6];
    const float* wo  = (const float*)d_in[7];
    const float* bo  = (const float*)d_in[8];
    const float* gq  = (const float*)d_in[9];
    const float* beq = (const float*)d_in[10];
    const float* gk  = (const float*)d_in[11];
    const float* bek = (const float*)d_in[12];
    const float* gv  = (const float*)d_in[13];
    const float* bev = (const float*)d_in[14];
    float* out = (float*)d_out;

    char* ws = (char*)d_ws;
    // xT   [0, 33554432)            bf16 [B][N][C]
    // wb   [33554432, 34340864)     bf16 [3][512][256]
    // ctx  [34340864, 34865152)     fp32 [B][8][64][64]
    // rs   [34865152, 34873344)     fp32 [B][512]
    // Weff [34873344, 35921920)     bf16 [B][256][512]
    u16* xT      = (u16*)(ws);
    u16* wb      = (u16*)(ws + 33554432ULL);
    float* ctx_a = (float*)(ws + 34340864ULL);
    float* rs    = (float*)(ws + 34865152ULL);
    u16* Weffb   = (u16*)(ws + 34873344ULL);

    cvtw_kernel<<<dim3(512, 3), 256, 0, stream>>>(wq, wk, wv, wb);
    transpose_kernel<<<dim3(256, 4, 4), 256, 0, stream>>>(x, xT);
    zero_kernel<<<dim3(520), 256, 0, stream>>>(ctx_a, 133120);  // ctx + rs contiguous

    kv_ctx_kernel<<<dim3(128, 4, 4), 256, 0, stream>>>(
        xT, wb, bk, bv, gk, bek, gv, bev, ctx_a, rs);

    weff_kernel<<<dim3(8, 4, 4), 256, 0, stream>>>(ctx_a, rs, wo, Weffb);

    q_out_kernel<<<dim3(256, 4), 256, 0, stream>>>(
        xT, wb, bq, gq, beq, Weffb, bo, out);
}